// Round 9
// baseline (157.510 us; speedup 1.0000x reference)
//
#include <hip/hip_runtime.h>
#include <hip/hip_bf16.h>

// BatchedNLM: per-neuron 2-layer GLU MLP.
//   state_trace (128,2048,32) f32, fc1_w (2048,32,256), fc1_b (2048,256),
//   fc2_w (2048,128,2), fc2_b (2048,2), T (1)  ->  out (128,2048) f32
//
// R15: DECISIVE no-barrier experiment. Surviving theory for the ~38-41us
// nlm invariant (5 structures, all counters idle, 64% no-issue cycles):
// block-wide staging barriers convoy all resident waves together. So:
//   prep (fused k0+k1, pure streaming): converts BOTH operands to bf16
//     MFMA-fragment layout in d_ws. k1: st -> st_t (A-frags, R13-proven).
//     k0: w1 -> w1t (B-frags, same column-load + fragment-write trick).
//   nlm: WAVE-AUTONOMOUS, 1 wave = 1 neuron, grid 2048 x 64thr. W1[n] in
//     64 VGPRs via 16 dense 1KB-per-instr loads; 8 batch tiles in pure
//     register compute; zero staging, 1-wave barriers only (free).
//     R11 died on the launch-bounds quirk (cap=256/min_waves; arg4->64);
//     (64,2) -> cap 128, liveness ~105.
//   transpose: unchanged.
//
// History: R4/R7/R9/R11 spills (toolchain: __launch_bounds__ 2nd arg 4 ->
// 64-reg cap, 2 -> 128). R5 DMA win vs spilling baseline. R6 41us.
// R8 NEUTRAL (41.4): occupancy x2. R10 NEUTRAL (45): cross-neuron DMA
// pipeline. R12/R13: st scatter removed -> neutral. R14 NEUTRAL (reg
// staging, 1 barrier). Falsified: VGPR cap, occupancy, pipelining,
// st scatter, DMA path. Remaining: barrier convoy. R15 tests it.

#define NN 2048

typedef __attribute__((ext_vector_type(8))) short short8;
typedef __attribute__((ext_vector_type(4))) float floatx4;
typedef __attribute__((ext_vector_type(4))) int int4v;

static __device__ __forceinline__ unsigned int pkbf(float a, float b) {
    __hip_bfloat162 h = __float22bfloat162_rn(make_float2(a, b));  // v_cvt_pk_bf16_f32
    return *(unsigned int*)&h;
}

static __device__ __forceinline__ float sigmoidf_(float x) {
    return __builtin_amdgcn_rcpf(1.0f + __expf(-x));  // mul+exp+add+rcp
}

// ---------------------------------------------------------------------------
// prep: fused streaming conversions, 256 thr, no barriers, latency-immune.
// blocks [0,512):   k1  st (128,2048,32) f32 -> st_t bf16 A-fragment-major.
//   st_t short idx: n*4096 + mt*512 + quad*128 + m*8 + e
//     = st[b=mt*16+m][n][k=quad*8+e]   (R13-proven)
// blocks [512,2560): k0  w1 (2048,32,256) f32 -> w1t bf16 B-fragment-major.
//   w1t short idx: n*8192 + p*512 + quad*128 + m*8 + e
//     = w1[n][k=quad*8+e][h=16p+m]
//   thread h reads 32 column dwords (256B/instr wave-coalesced), writes
//   4x16B fragment stores (wave covers 4KB fully).
// ---------------------------------------------------------------------------
__global__ __launch_bounds__(256)
void prep_kernel(const float* __restrict__ st, short* __restrict__ st_t,
                 const float* __restrict__ w1, short* __restrict__ w1t)
{
    const int bid = blockIdx.x;
    const int t   = threadIdx.x;       // 0..255

    if (bid < 512) {
        // ---- k1: st transpose (verbatim R13) ----
        const int lane = t & 63;
        const int wv   = t >> 6;            // 0..3
        const int mt   = bid & 7;           // batch tile
        const int g    = bid >> 3;          // 0..63 n-group
        const int m    = lane & 15;
        const int quad = lane >> 4;

        const int b = mt * 16 + m;
        const float* src = st + (size_t)b * (NN * 32) + (size_t)quad * 8;
        short* dstbase = st_t + (size_t)mt * 512 + (size_t)lane * 8;

        const int n0 = g * 32 + wv;         // wave handles n = n0 + 4*i, i<8
        #pragma unroll
        for (int i = 0; i < 8; ++i) {
            const int n = n0 + i * 4;
            floatx4 a0 = *(const floatx4*)(src + (size_t)n * 32);
            floatx4 a1 = *(const floatx4*)(src + (size_t)n * 32 + 4);
            union { int4v iv; short8 s; } u;
            u.iv[0] = pkbf(a0[0], a0[1]);
            u.iv[1] = pkbf(a0[2], a0[3]);
            u.iv[2] = pkbf(a1[0], a1[1]);
            u.iv[3] = pkbf(a1[2], a1[3]);
            *(short8*)(dstbase + (size_t)n * 4096) = u.s;
        }
    } else {
        // ---- k0: w1 -> bf16 fragment-major ----
        const int n = bid - 512;
        const int h = t;                                   // owned column
        const float* gW = w1 + (size_t)n * 8192 + h;
        float wr[32];
        #pragma unroll
        for (int k = 0; k < 32; ++k)
            wr[k] = gW[(size_t)k * 256];                   // 256B/instr coalesced

        short* dst = w1t + (size_t)n * 8192 + ((h >> 4) * 512) + ((h & 15) * 8);
        #pragma unroll
        for (int q = 0; q < 4; ++q) {                      // k-block q: k=8q..8q+7
            union { int4v iv; short8 s; } u;
            #pragma unroll
            for (int e = 0; e < 4; ++e)
                u.iv[e] = pkbf(wr[q * 8 + 2 * e], wr[q * 8 + 2 * e + 1]);
            *(short8*)(dst + q * 128) = u.s;
        }
    }
}

// ---------------------------------------------------------------------------
// nlm: wave-autonomous. 1 wave = 1 neuron. Grid 2048 x 64.
// ---------------------------------------------------------------------------
__global__ __launch_bounds__(64, 2)   // cap 128 VGPR (quirk: 256/min_waves)
void nlm_kernel(const short* __restrict__ st_t,
                const short* __restrict__ w1t,
                const float* __restrict__ b1,
                const float* __restrict__ w2,
                const float* __restrict__ b2,
                const float* __restrict__ Tp,
                float* __restrict__ out_t)
{
    const int n    = blockIdx.x;
    const int lane = threadIdx.x;    // 0..63
    const int m    = lane & 15;      // A row / C col
    const int quad = lane >> 4;      // k-quad / C row group

    __shared__ float4 ldsP[128];     // {b1[h], b1[128+h], w2[2h], w2[2h+1]}
    __shared__ float  ldsO[128];

    // ---- params (each lane fills 2 entries) ----
    {
        const float* b1p = b1 + (size_t)n * 256;
        const float* w2p = w2 + (size_t)n * 256;
        #pragma unroll
        for (int j = 0; j < 2; ++j) {
            const int hh = lane + 64 * j;
            ldsP[hh] = make_float4(b1p[hh], b1p[128 + hh],
                                   w2p[2 * hh], w2p[2 * hh + 1]);
        }
    }
    const float bb0  = b2[n * 2 + 0];
    const float bb1  = b2[n * 2 + 1];
    const float invT = 1.0f / Tp[0];

    // ---- W1[n] -> 16 B-fragments in 64 VGPRs. 16 x 1KB-per-instr dense. ----
    short8 wf[16];
    {
        const short* gw = w1t + (size_t)n * 8192 + (size_t)lane * 8;
        #pragma unroll
        for (int p = 0; p < 16; ++p)
            wf[p] = *(const short8*)(gw + p * 512);
    }

    __syncthreads();   // 1-wave block: ldsP visibility, ~free

    const short* ga = st_t + (size_t)n * 4096 + (size_t)lane * 8;
    short8 acur = *(const short8*)ga;    // mt = 0

    #pragma unroll 1
    for (int mt = 0; mt < 8; ++mt) {
        // one-ahead A prefetch (independent -> issues before compute)
        short8 anext = acur;
        if (mt < 7) anext = *(const short8*)(ga + (mt + 1) * 512);

        float pacc[4][2];
        #pragma unroll
        for (int r = 0; r < 4; ++r)
            pacc[r][0] = pacc[r][1] = 0.0f;

        #pragma unroll
        for (int p = 0; p < 8; ++p) {
            float4 prm = ldsP[p * 16 + m];   // {bias_a, bias_b, w2a, w2b}, h=16p+m
            floatx4 ca = {prm.x, prm.x, prm.x, prm.x};
            floatx4 cb = {prm.y, prm.y, prm.y, prm.y};
            floatx4 xa = __builtin_amdgcn_mfma_f32_16x16x32_bf16(acur, wf[p],     ca, 0, 0, 0);
            floatx4 xb = __builtin_amdgcn_mfma_f32_16x16x32_bf16(acur, wf[p + 8], cb, 0, 0, 0);
            #pragma unroll
            for (int r = 0; r < 4; ++r) {
                float glu = xa[r] * sigmoidf_(xb[r]);
                pacc[r][0] += glu * prm.z;
                pacc[r][1] += glu * prm.w;
            }
        }

        #pragma unroll
        for (int r = 0; r < 4; ++r) {
            float s0 = pacc[r][0];
            float s1 = pacc[r][1];
            s0 += __shfl_xor(s0, 1);  s1 += __shfl_xor(s1, 1);
            s0 += __shfl_xor(s0, 2);  s1 += __shfl_xor(s1, 2);
            s0 += __shfl_xor(s0, 4);  s1 += __shfl_xor(s1, 4);
            s0 += __shfl_xor(s0, 8);  s1 += __shfl_xor(s1, 8);
            if (m == 0) {
                const int b = mt * 16 + quad * 4 + r;
                float x0 = s0 + bb0;
                float x1 = s1 + bb1;
                ldsO[b] = x0 * sigmoidf_(x1) * invT;
            }
        }

        acur = anext;
    }

    __syncthreads();   // ldsO visible, ~free

    // coalesced 512B row into out_t (2048,128)
    out_t[(size_t)n * 128 + lane]      = ldsO[lane];
    out_t[(size_t)n * 128 + 64 + lane] = ldsO[64 + lane];
}

// Transpose out_t (2048,128) -> out (128,2048). 32x32 tiles, 256 blocks.
__global__ __launch_bounds__(256)
void transpose_kernel(const float* __restrict__ out_t, float* __restrict__ out)
{
    __shared__ float tile[32][33];
    const int t    = threadIdx.x;
    const int bidx = blockIdx.x;           // 0..255
    const int n0   = (bidx & 63) * 32;     // 64 n-tiles
    const int b0   = (bidx >> 6) * 32;     // 4 b-tiles

    const int tx = t & 31;
    const int ty = t >> 5;                 // 0..7

    #pragma unroll
    for (int i = 0; i < 4; ++i) {
        const int nl = ty + i * 8;
        tile[nl][tx] = out_t[(size_t)(n0 + nl) * 128 + b0 + tx];
    }

    __syncthreads();

    #pragma unroll
    for (int i = 0; i < 4; ++i) {
        const int bl = ty + i * 8;
        out[(size_t)(b0 + bl) * NN + n0 + tx] = tile[tx][bl];
    }
}

extern "C" void kernel_launch(void* const* d_in, const int* in_sizes, int n_in,
                              void* d_out, int out_size, void* d_ws, size_t ws_size,
                              hipStream_t stream) {
    const float* st = (const float*)d_in[0];
    const float* w1 = (const float*)d_in[1];
    const float* b1 = (const float*)d_in[2];
    const float* w2 = (const float*)d_in[3];
    const float* b2 = (const float*)d_in[4];
    const float* T  = (const float*)d_in[5];
    float* out   = (float*)d_out;
    float* out_t = (float*)d_ws;                          // [0, 1 MB)
    short* st_t  = (short*)((char*)d_ws + (2u  << 20));   // [2, ~19 MB)
    short* w1t   = (short*)((char*)d_ws + (32u << 20));   // [32, 64 MB)

    prep_kernel<<<dim3(2560), dim3(256), 0, stream>>>(st, st_t, w1, w1t);
    nlm_kernel<<<dim3(NN), dim3(64), 0, stream>>>(st_t, w1t, b1, w2, b2, T, out_t);
    transpose_kernel<<<dim3(256), dim3(256), 0, stream>>>(out_t, out);
}

// Round 11
// 155.293 us; speedup vs baseline: 1.0143x; 1.0143x over previous
//
#include <hip/hip_runtime.h>
#include <hip/hip_bf16.h>

// BatchedNLM: per-neuron 2-layer GLU MLP.
//   state_trace (128,2048,32) f32, fc1_w (2048,32,256), fc1_b (2048,256),
//   fc2_w (2048,128,2), fc2_b (2048,2), T (1)  ->  out (128,2048) f32
//
// R16b: RERUN of R16 (previous round died on "MI355X container failed
// twice" — broker infrastructure, no counters, hypothesis untested).
//
// R16: SINGLE FUSED KERNEL, wave-per-neuron, zero intermediates.
// Purpose is dual: (1) best-roofline structure (no k1/prep/transpose round
// trips, no launch gaps, 96MB read + ~17MB write ~ 15-20us); (2) perfect
// attribution — with fills the only other dispatches, nlm's duration is
// total - 82us and MUST appear in the rocprof top-5, ending 4 rounds of
// invisible-nlm guesswork.
//   - one wave per neuron (grid 2048 x 64thr), __launch_bounds__(64,2)
//     (toolchain quirk: VGPR cap = 256/min_waves; arg 2 -> 128).
//   - W1 loaded DIRECTLY from natural layout in fragment order:
//     8 iters x 16 independent dword loads (256B/instr, 4x64B segments),
//     liveness 16 floats/iter -> wf[16] (64 VGPR). Unlike R11 (which died
//     on the 64-cap + full hoist), per-iter liveness fits under 128.
//   - st read natural (2x16B per mt, one-ahead prefetch), pkbf in regs.
//   - out written directly, scattered 4B stores from m==0 lanes
//     (~16MB effective, == cost of the out_t+transpose path it replaces).
//   - no barriers except one free 1-wave sync after the private-LDS
//     param fill.
//
// History: R4/R7/R9/R11 spills (launch-bounds quirk). R5 DMA win.
// R6 41us. R8 NEUTRAL 41.4 (2x occupancy). R10 NEUTRAL 45 (pipelined).
// R12/R13 NEUTRAL (st scatter removed). R14 NEUTRAL (reg staging, 1
// barrier). R15 NEUTRAL (wave-autonomous + pre-transposed operands).
// Falsified: VGPR cap, occupancy, pipelining, st scatter, DMA path,
// barrier convoy. R16 = cleanest structure + clean measurement; if it
// also lands ~40us, the floor is not structural -> revert R8 and stop.

#define NN 2048

typedef __attribute__((ext_vector_type(8))) short short8;
typedef __attribute__((ext_vector_type(4))) float floatx4;
typedef __attribute__((ext_vector_type(4))) int int4v;

static __device__ __forceinline__ unsigned int pkbf(float a, float b) {
    __hip_bfloat162 h = __float22bfloat162_rn(make_float2(a, b));  // v_cvt_pk_bf16_f32
    return *(unsigned int*)&h;
}

static __device__ __forceinline__ float sigmoidf_(float x) {
    return __builtin_amdgcn_rcpf(1.0f + __expf(-x));  // mul+exp+add+rcp
}

static __device__ __forceinline__ short8 pack_afrag(floatx4 a0, floatx4 a1) {
    union { int4v i; short8 s; } u;
    u.i[0] = pkbf(a0[0], a0[1]);
    u.i[1] = pkbf(a0[2], a0[3]);
    u.i[2] = pkbf(a1[0], a1[1]);
    u.i[3] = pkbf(a1[2], a1[3]);
    return u.s;
}

__global__ __launch_bounds__(64, 2)   // VGPR cap 128 (quirk: 256/min_waves)
void nlm_kernel(const float* __restrict__ st,
                const float* __restrict__ w1,
                const float* __restrict__ b1,
                const float* __restrict__ w2,
                const float* __restrict__ b2,
                const float* __restrict__ Tp,
                float* __restrict__ out)
{
    const int n    = blockIdx.x;
    const int lane = threadIdx.x;    // 0..63 (one wave)
    const int m    = lane & 15;      // A row (batch-in-tile) / C col (h-in-tile)
    const int quad = lane >> 4;      // k-quad / C row group

    __shared__ float4 ldsP[128];     // {b1[h], b1[128+h], w2[2h], w2[2h+1]}

    // ---- params: 64 lanes x 2 entries (private to this wave's block) ----
    {
        const float* b1p = b1 + (size_t)n * 256;
        const float* w2p = w2 + (size_t)n * 256;
        #pragma unroll
        for (int j = 0; j < 2; ++j) {
            const int hh = lane + 64 * j;
            ldsP[hh] = make_float4(b1p[hh], b1p[128 + hh],
                                   w2p[2 * hh], w2p[2 * hh + 1]);
        }
    }
    const float bb0  = b2[n * 2 + 0];
    const float bb1  = b2[n * 2 + 1];
    const float invT = 1.0f / Tp[0];

    // ---- first A-tile (mt=0) issued early ----
    const float* sbase = st + (size_t)n * 32 + (size_t)quad * 8;
    floatx4 a0 = *(const floatx4*)(sbase + (size_t)m * (NN * 32));
    floatx4 a1 = *(const floatx4*)(sbase + (size_t)m * (NN * 32) + 4);

    // ---- W1 -> 16 bf16 B-fragments (64 VGPR), straight from natural layout.
    //      wf[p][e] = w1[n][k=quad*8+e][h=16p+m].
    //      Per instr: m=0..15 contiguous -> 4 x 64B segments (256B).
    //      2 tiles/iter = 16 independent loads in flight; liveness 16 f32. ----
    short8 wf[16];
    {
        const float* gW = w1 + (size_t)n * 8192 + (size_t)quad * 2048 + m;
        #pragma unroll 1
        for (int pp = 0; pp < 8; ++pp) {
            float v0[8], v1[8];
            #pragma unroll
            for (int e = 0; e < 8; ++e) {
                v0[e] = gW[e * 256 + (2 * pp) * 16];
                v1[e] = gW[e * 256 + (2 * pp + 1) * 16];
            }
            union { int4v iv; short8 s; } u0, u1;
            #pragma unroll
            for (int e = 0; e < 4; ++e) {
                u0.iv[e] = pkbf(v0[2 * e], v0[2 * e + 1]);
                u1.iv[e] = pkbf(v1[2 * e], v1[2 * e + 1]);
            }
            wf[2 * pp]     = u0.s;
            wf[2 * pp + 1] = u1.s;
        }
    }

    __syncthreads();   // 1-wave block: ldsP visibility; ~free

    short8 acur = pack_afrag(a0, a1);

    #pragma unroll 1
    for (int mt = 0; mt < 8; ++mt) {
        // one-ahead A prefetch (independent; issues ahead of the compute)
        floatx4 p0 = a0, p1 = a1;
        if (mt < 7) {
            const float* sp = sbase + (size_t)((mt + 1) * 16 + m) * (NN * 32);
            p0 = *(const floatx4*)sp;
            p1 = *(const floatx4*)(sp + 4);
        }

        float pacc[4][2];
        #pragma unroll
        for (int r = 0; r < 4; ++r)
            pacc[r][0] = pacc[r][1] = 0.0f;

        #pragma unroll
        for (int p = 0; p < 8; ++p) {
            float4 prm = ldsP[p * 16 + m];   // {bias_a, bias_b, w2a, w2b}, h=16p+m
            floatx4 ca = {prm.x, prm.x, prm.x, prm.x};   // fc1 bias as C-init
            floatx4 cb = {prm.y, prm.y, prm.y, prm.y};
            floatx4 xa = __builtin_amdgcn_mfma_f32_16x16x32_bf16(acur, wf[p],     ca, 0, 0, 0);
            floatx4 xb = __builtin_amdgcn_mfma_f32_16x16x32_bf16(acur, wf[p + 8], cb, 0, 0, 0);
            #pragma unroll
            for (int r = 0; r < 4; ++r) {
                float glu = xa[r] * sigmoidf_(xb[r]);
                pacc[r][0] += glu * prm.z;
                pacc[r][1] += glu * prm.w;
            }
        }

        // reduce fc2 partials over the 16 m-lanes of each quad; write out
        #pragma unroll
        for (int r = 0; r < 4; ++r) {
            float s0 = pacc[r][0];
            float s1 = pacc[r][1];
            s0 += __shfl_xor(s0, 1);  s1 += __shfl_xor(s1, 1);
            s0 += __shfl_xor(s0, 2);  s1 += __shfl_xor(s1, 2);
            s0 += __shfl_xor(s0, 4);  s1 += __shfl_xor(s1, 4);
            s0 += __shfl_xor(s0, 8);  s1 += __shfl_xor(s1, 8);
            if (m == 0) {
                const int b = mt * 16 + quad * 4 + r;
                float x0 = s0 + bb0;
                float x1 = s1 + bb1;
                out[(size_t)b * NN + n] = x0 * sigmoidf_(x1) * invT;
            }
        }

        acur = pack_afrag(p0, p1);
        a0 = p0; a1 = p1;
    }
}

extern "C" void kernel_launch(void* const* d_in, const int* in_sizes, int n_in,
                              void* d_out, int out_size, void* d_ws, size_t ws_size,
                              hipStream_t stream) {
    const float* st = (const float*)d_in[0];
    const float* w1 = (const float*)d_in[1];
    const float* b1 = (const float*)d_in[2];
    const float* w2 = (const float*)d_in[3];
    const float* b2 = (const float*)d_in[4];
    const float* T  = (const float*)d_in[5];
    float* out = (float*)d_out;

    nlm_kernel<<<dim3(NN), dim3(64), 0, stream>>>(st, w1, b1, w2, b2, T, out);
}